// Round 7
// baseline (209.005 us; speedup 1.0000x reference)
//
#include <hip/hip_runtime.h>
#include <math.h>

typedef __attribute__((ext_vector_type(8)))  short bf16x8;
typedef __attribute__((ext_vector_type(4)))  float f32x4;
typedef __attribute__((ext_vector_type(2)))  float f32x2;
typedef __attribute__((ext_vector_type(16))) int   i32x16;

constexpr int kN   = 50000;
constexpr int kR   = 8;
constexpr int kIn  = 128;
constexpr int kHid = 128;
constexpr int kOut = 40;
constexpr int kNT  = 16;              // dst nodes per block
constexpr int kLds = 1032;            // ushort row stride (16B-aligned rows)
constexpr float kBnEps = 1e-5f;

// bf16 helpers (RNE; used only in prep, off the critical path)
__device__ inline ushort f2bf(float x) {
    uint u = __float_as_uint(x);
    u += 0x7FFFu + ((u >> 16) & 1u);
    return (ushort)(u >> 16);
}

// ---------------------------------------------------------------------------
// Guaranteed-SMEM load of 16 consecutive ints (edge metadata).
// ---------------------------------------------------------------------------
__device__ __forceinline__ void sload_meta(const int* pi, const int* pt,
                                           i32x16& vi, i32x16& vt)
{
    asm volatile("s_load_dwordx16 %0, %2, 0x0\n\t"
                 "s_load_dwordx16 %1, %3, 0x0\n\t"
                 "s_waitcnt lgkmcnt(0)"
                 : "=s"(vi), "=s"(vt) : "s"(pi), "s"(pt));
}

// ---------------------------------------------------------------------------
// prep: fused  (a) cast x fp32->bf16   [blocks 0..3124, 256 thr x 8 elems]
//              (b) pack W1 into MFMA B-fragment order [blocks 3125..3188]
//              (c) pack W2                           [blocks 3189..3212]
// Fragment f = nt*32 + kt; lane L holds B[n = nt*16 + (L&15)][k = kt*32 + (L>>4)*8 + j].
// ---------------------------------------------------------------------------
__device__ __forceinline__ void pack_unit(const float* __restrict__ W,
                                          ushort* __restrict__ dst,
                                          int N, int frag, int lane)
{
    const int kt = frag & 31;
    const int nt = frag >> 5;
    const int n  = nt * 16 + (lane & 15);
    const int q  = lane >> 4;
    ushort hv[8];
    #pragma unroll
    for (int j = 0; j < 8; ++j) {
        const int k = kt * 32 + q * 8 + j;
        hv[j] = f2bf((n < N) ? W[(size_t)k * N + n] : 0.f);
    }
    const size_t o = ((size_t)frag * 64 + lane) * 8;
    *(ushort4*)&dst[o]     = make_ushort4(hv[0], hv[1], hv[2], hv[3]);
    *(ushort4*)&dst[o + 4] = make_ushort4(hv[4], hv[5], hv[6], hv[7]);
}

__global__ __launch_bounds__(256)
void prep(const float* __restrict__ x,  ushort* __restrict__ xb,
          const float* __restrict__ W1, ushort* __restrict__ W1hi,
          const float* __restrict__ W2, ushort* __restrict__ W2hi)
{
    const int b   = blockIdx.x;
    const int tid = threadIdx.x;
    if (b < 3125) {
        const size_t i = ((size_t)b * 256 + tid) * 8;
        const float4 v0 = *(const float4*)&x[i];
        const float4 v1 = *(const float4*)&x[i + 4];
        *(ushort4*)&xb[i]     = make_ushort4(f2bf(v0.x), f2bf(v0.y), f2bf(v0.z), f2bf(v0.w));
        *(ushort4*)&xb[i + 4] = make_ushort4(f2bf(v1.x), f2bf(v1.y), f2bf(v1.z), f2bf(v1.w));
    } else if (b < 3125 + 64) {
        pack_unit(W1, W1hi, kHid, (b - 3125) * 4 + (tid >> 6), tid & 63);
    } else {
        const int frag = (b - 3189) * 4 + (tid >> 6);
        if (frag < 96) pack_unit(W2, W2hi, kOut, frag, tid & 63);
    }
}

// ---------------------------------------------------------------------------
// Phase A: 8 waves x 2 sequential nodes; lane owns channel pair d2, d2+1
// (one packed bf16 dword per gather). Metadata via s_load (SGPRs, no
// readlanes); 3-VALU accumulate per edge; 5-VALU pack/store per relation.
// ---------------------------------------------------------------------------
#define CVT_ACC(T, B) {                                                     \
    f32x2 v;                                                                \
    v.x = __uint_as_float((B) << 16);                                       \
    v.y = __uint_as_float((B) & 0xffff0000u);                               \
    if      ((T) == 0) a0 += v; else if ((T) == 1) a1 += v;                 \
    else if ((T) == 2) a2 += v; else if ((T) == 3) a3 += v;                 \
    else if ((T) == 4) a4 += v; else if ((T) == 5) a5 += v;                 \
    else if ((T) == 6) a6 += v; else               a7 += v; }

#define GATH(BV, S) \
    const uint BV = *(const uint*)(feat + (size_t)(S) * 128 + d2);

#define STORE_AGG(RR, AV) {                                                 \
    const uint px = (__float_as_uint(AV.x) + 0x8000u) >> 16;                \
    const uint py = (__float_as_uint(AV.y) + 0x8000u) & 0xffff0000u;        \
    *(uint*)&aggHi[n][(RR) * 128 + d2] = px | py; }

__device__ __forceinline__ void phaseA_bf16(const ushort* __restrict__ feat,
                                            const int* __restrict__ ptr,
                                            const int* __restrict__ idx,
                                            const int* __restrict__ etype,
                                            int base, ushort (*aggHi)[kLds])
{
    const int lane = threadIdx.x & 63;
    const int wid  = threadIdx.x >> 6;            // 8 waves
    const int d2   = lane * 2;

    #pragma unroll
    for (int t = 0; t < 2; ++t) {
        const int n    = wid * 2 + t;
        const int node = base + n;
        const int p0   = __builtin_amdgcn_readfirstlane(ptr[node]);
        const int deg  = __builtin_amdgcn_readfirstlane(ptr[node + 1]) - p0;

        f32x2 a0 = {0.f,0.f}, a1 = {0.f,0.f}, a2 = {0.f,0.f}, a3 = {0.f,0.f};
        f32x2 a4 = {0.f,0.f}, a5 = {0.f,0.f}, a6 = {0.f,0.f}, a7 = {0.f,0.f};

        if (deg == 16) {                          // fixed-degree fast path
            i32x16 vi, vt;
            sload_meta(idx + p0, etype + p0, vi, vt);
            GATH(b0,  vi[0])  GATH(b1,  vi[1])  GATH(b2,  vi[2])  GATH(b3,  vi[3])
            GATH(b4,  vi[4])  GATH(b5,  vi[5])  GATH(b6,  vi[6])  GATH(b7,  vi[7])
            GATH(b8,  vi[8])  GATH(b9,  vi[9])  GATH(b10, vi[10]) GATH(b11, vi[11])
            GATH(b12, vi[12]) GATH(b13, vi[13]) GATH(b14, vi[14]) GATH(b15, vi[15])
            CVT_ACC(vt[0],  b0)  CVT_ACC(vt[1],  b1)  CVT_ACC(vt[2],  b2)
            CVT_ACC(vt[3],  b3)  CVT_ACC(vt[4],  b4)  CVT_ACC(vt[5],  b5)
            CVT_ACC(vt[6],  b6)  CVT_ACC(vt[7],  b7)  CVT_ACC(vt[8],  b8)
            CVT_ACC(vt[9],  b9)  CVT_ACC(vt[10], b10) CVT_ACC(vt[11], b11)
            CVT_ACC(vt[12], b12) CVT_ACC(vt[13], b13) CVT_ACC(vt[14], b14)
            CVT_ACC(vt[15], b15)
        } else {                                  // generic fallback (never hit)
            for (int e = p0; e < p0 + deg; ++e) {
                const int src = __builtin_amdgcn_readfirstlane(idx[e]);
                const int et  = __builtin_amdgcn_readfirstlane(etype[e]);
                const uint u  = *(const uint*)(feat + (size_t)src * 128 + d2);
                CVT_ACC(et, u)
            }
        }
        STORE_AGG(0, a0) STORE_AGG(1, a1) STORE_AGG(2, a2) STORE_AGG(3, a3)
        STORE_AGG(4, a4) STORE_AGG(5, a5) STORE_AGG(6, a6) STORE_AGG(7, a7)
    }
}

// ---------------------------------------------------------------------------
// Layer 1: h1 = bf16( relu(bn( (sum_r agg_r @ W1[r]) / deg )) )
// Phase B: wave w owns n-tile w; dual accumulators break the MFMA dep chain.
// ---------------------------------------------------------------------------
__global__ __launch_bounds__(512, 4)
void rgcn_layer1(const ushort* __restrict__ xb,
                 const ushort* __restrict__ W1hi,
                 const float* __restrict__ gamma, const float* __restrict__ beta,
                 const float* __restrict__ mean,  const float* __restrict__ var,
                 const int* __restrict__ ptr, const int* __restrict__ idx,
                 const int* __restrict__ etype,
                 ushort* __restrict__ h1b)
{
    __shared__ ushort aggHi[kNT][kLds];           // 33 KB
    const int tid  = threadIdx.x;
    const int base = blockIdx.x * kNT;

    phaseA_bf16(xb, ptr, idx, etype, base, aggHi);
    __syncthreads();

    const int lane = tid & 63;
    const int wid  = tid >> 6;                    // n-tile owned by this wave
    const int m    = lane & 15;
    const int q    = lane >> 4;

    const bf16x8* Bh = (const bf16x8*)W1hi + (size_t)wid * 32 * 64 + lane;
    f32x4 accA = {0.f, 0.f, 0.f, 0.f};
    f32x4 accB = {0.f, 0.f, 0.f, 0.f};

    #pragma unroll 4
    for (int kt = 0; kt < 32; kt += 2) {
        const bf16x8 ah0 = *(const bf16x8*)&aggHi[m][kt * 32 + q * 8];
        const bf16x8 bh0 = Bh[(size_t)kt * 64];
        const bf16x8 ah1 = *(const bf16x8*)&aggHi[m][(kt + 1) * 32 + q * 8];
        const bf16x8 bh1 = Bh[(size_t)(kt + 1) * 64];
        accA = __builtin_amdgcn_mfma_f32_16x16x32_bf16(ah0, bh0, accA, 0, 0, 0);
        accB = __builtin_amdgcn_mfma_f32_16x16x32_bf16(ah1, bh1, accB, 0, 0, 0);
    }
    const f32x4 acc = accA + accB;

    // Epilogue: deg norm + BN + ReLU, write bf16 h1
    const int c = wid * 16 + m;
    const float g  = gamma[c] * rsqrtf(var[c] + kBnEps);
    const float mu = mean[c];
    const float bt = beta[c];
    #pragma unroll
    for (int i = 0; i < 4; ++i) {
        const int node = base + q * 4 + i;
        const float invdeg = 1.0f / (float)(ptr[node + 1] - ptr[node]);
        float v = (acc[i] * invdeg - mu) * g + bt;
        v = fmaxf(v, 0.f);
        h1b[(size_t)node * kHid + c] = (ushort)((__float_as_uint(v) + 0x8000u) >> 16);
    }
}

// ---------------------------------------------------------------------------
// Layer 2: out = log_softmax( (sum_r agg_r @ W2[r]) / deg ), N padded 40->48
// ---------------------------------------------------------------------------
__global__ __launch_bounds__(512, 4)
void rgcn_layer2(const ushort* __restrict__ h1b,
                 const ushort* __restrict__ W2hi,
                 const int* __restrict__ ptr, const int* __restrict__ idx,
                 const int* __restrict__ etype,
                 float* __restrict__ out)
{
    __shared__ ushort aggHi[kNT][kLds];           // 33 KB
    __shared__ float logits[kNT][48];             // 3 KB
    const int tid  = threadIdx.x;
    const int base = blockIdx.x * kNT;

    phaseA_bf16(h1b, ptr, idx, etype, base, aggHi);
    __syncthreads();

    const int lane = tid & 63;
    const int wid  = tid >> 6;
    const int m    = lane & 15;
    const int q    = lane >> 4;

    if (wid < 3) {                                // n-tiles 0..2 cover 48 cols
        const bf16x8* Bh = (const bf16x8*)W2hi + (size_t)wid * 32 * 64 + lane;
        f32x4 accA = {0.f, 0.f, 0.f, 0.f};
        f32x4 accB = {0.f, 0.f, 0.f, 0.f};
        #pragma unroll 4
        for (int kt = 0; kt < 32; kt += 2) {
            const bf16x8 ah0 = *(const bf16x8*)&aggHi[m][kt * 32 + q * 8];
            const bf16x8 bh0 = Bh[(size_t)kt * 64];
            const bf16x8 ah1 = *(const bf16x8*)&aggHi[m][(kt + 1) * 32 + q * 8];
            const bf16x8 bh1 = Bh[(size_t)(kt + 1) * 64];
            accA = __builtin_amdgcn_mfma_f32_16x16x32_bf16(ah0, bh0, accA, 0, 0, 0);
            accB = __builtin_amdgcn_mfma_f32_16x16x32_bf16(ah1, bh1, accB, 0, 0, 0);
        }
        const f32x4 acc = accA + accB;
        const int n = wid * 16 + m;               // logit column
        if (n < kOut) {
            #pragma unroll
            for (int i = 0; i < 4; ++i) {
                const int node = base + q * 4 + i;
                const float invdeg = 1.0f / (float)(ptr[node + 1] - ptr[node]);
                logits[q * 4 + i][n] = acc[i] * invdeg;
            }
        }
    }
    __syncthreads();

    // log_softmax: wave w handles nodes w*2, w*2+1
    #pragma unroll
    for (int i = 0; i < 2; ++i) {
        const int nrow = wid * 2 + i;
        const int node = base + nrow;
        const float v = (lane < kOut) ? logits[nrow][lane] : -INFINITY;
        float mx = v;
        #pragma unroll
        for (int off = 32; off > 0; off >>= 1)
            mx = fmaxf(mx, __shfl_xor(mx, off, 64));
        float s = (lane < kOut) ? __expf(v - mx) : 0.f;
        #pragma unroll
        for (int off = 32; off > 0; off >>= 1)
            s += __shfl_xor(s, off, 64);
        if (lane < kOut)
            out[(size_t)node * kOut + lane] = v - mx - __logf(s);
    }
}

// ---------------------------------------------------------------------------
extern "C" void kernel_launch(void* const* d_in, const int* in_sizes, int n_in,
                              void* d_out, int out_size, void* d_ws, size_t ws_size,
                              hipStream_t stream)
{
    const float* x     = (const float*)d_in[0];
    const float* W1    = (const float*)d_in[1];
    const float* W2    = (const float*)d_in[2];
    const float* gamma = (const float*)d_in[3];
    const float* beta  = (const float*)d_in[4];
    const float* mean  = (const float*)d_in[5];
    const float* var   = (const float*)d_in[6];
    const int*   ptr   = (const int*)d_in[7];
    const int*   idx   = (const int*)d_in[8];
    const int*   et    = (const int*)d_in[9];
    float*       out   = (float*)d_out;

    // Workspace (~26 MB)
    char* ws = (char*)d_ws;
    ushort* h1b  = (ushort*)ws;                              // 12,800,000 B
    ushort* xb   = (ushort*)(ws + 12800000);                 // 12,800,000 B
    ushort* W1hi = (ushort*)(ws + 25600000);                 //    262,144 B
    ushort* W2hi = (ushort*)(ws + 25600000 + 262144);        //     98,304 B

    prep<<<dim3(3125 + 64 + 24), dim3(256), 0, stream>>>(x, xb, W1, W1hi, W2, W2hi);

    dim3 grid(kN / kNT), block(512);
    rgcn_layer1<<<grid, block, 0, stream>>>(xb, W1hi, gamma, beta, mean, var,
                                            ptr, idx, et, h1b);
    rgcn_layer2<<<grid, block, 0, stream>>>(h1b, W2hi, ptr, idx, et, out);
}

// Round 8
// 198.115 us; speedup vs baseline: 1.0550x; 1.0550x over previous
//
#include <hip/hip_runtime.h>
#include <math.h>

typedef __attribute__((ext_vector_type(8))) short bf16x8;
typedef __attribute__((ext_vector_type(4))) float f32x4;
typedef __attribute__((ext_vector_type(2))) float f32x2;

constexpr int kN   = 50000;
constexpr int kR   = 8;
constexpr int kIn  = 128;
constexpr int kHid = 128;
constexpr int kOut = 40;
constexpr int kNT  = 16;              // dst nodes per block
constexpr int kLds = 1032;            // ushort row stride (16B-aligned rows)
constexpr float kBnEps = 1e-5f;

// bf16 RNE (prep only, off the critical path)
__device__ inline ushort f2bf(float x) {
    uint u = __float_as_uint(x);
    u += 0x7FFFu + ((u >> 16) & 1u);
    return (ushort)(u >> 16);
}

// ---------------------------------------------------------------------------
// prep: fused  (a) cast x fp32->bf16   [blocks 0..3124, 256 thr x 8 elems]
//              (b) pack W1 into MFMA B-fragment order [blocks 3125..3188]
//              (c) pack W2                            [blocks 3189..3212]
// Fragment f = nt*32 + kt; lane L holds B[n = nt*16 + (L&15)][k = kt*32 + (L>>4)*8 + j].
// ---------------------------------------------------------------------------
__device__ __forceinline__ void pack_unit(const float* __restrict__ W,
                                          ushort* __restrict__ dst,
                                          int N, int frag, int lane)
{
    const int kt = frag & 31;
    const int nt = frag >> 5;
    const int n  = nt * 16 + (lane & 15);
    const int q  = lane >> 4;
    ushort hv[8];
    #pragma unroll
    for (int j = 0; j < 8; ++j) {
        const int k = kt * 32 + q * 8 + j;
        hv[j] = f2bf((n < N) ? W[(size_t)k * N + n] : 0.f);
    }
    const size_t o = ((size_t)frag * 64 + lane) * 8;
    *(ushort4*)&dst[o]     = make_ushort4(hv[0], hv[1], hv[2], hv[3]);
    *(ushort4*)&dst[o + 4] = make_ushort4(hv[4], hv[5], hv[6], hv[7]);
}

__global__ __launch_bounds__(256)
void prep(const float* __restrict__ x,  ushort* __restrict__ xb,
          const float* __restrict__ W1, ushort* __restrict__ W1hi,
          const float* __restrict__ W2, ushort* __restrict__ W2hi)
{
    const int b   = blockIdx.x;
    const int tid = threadIdx.x;
    if (b < 3125) {
        const size_t i = ((size_t)b * 256 + tid) * 8;
        const float4 v0 = *(const float4*)&x[i];
        const float4 v1 = *(const float4*)&x[i + 4];
        *(ushort4*)&xb[i]     = make_ushort4(f2bf(v0.x), f2bf(v0.y), f2bf(v0.z), f2bf(v0.w));
        *(ushort4*)&xb[i + 4] = make_ushort4(f2bf(v1.x), f2bf(v1.y), f2bf(v1.z), f2bf(v1.w));
    } else if (b < 3125 + 64) {
        pack_unit(W1, W1hi, kHid, (b - 3125) * 4 + (tid >> 6), tid & 63);
    } else {
        const int frag = (b - 3189) * 4 + (tid >> 6);
        if (frag < 96) pack_unit(W2, W2hi, kOut, frag, tid & 63);
    }
}

// ---------------------------------------------------------------------------
// Phase A: 8 waves x 2 consecutive nodes (32 contiguous edges -> ONE idx load
// + ONE etype load serves both). Metadata to scalars via readlane; 3-VALU
// accumulate per edge (shl/and cvt + packed f32x2 add); 5-VALU pack/store.
// No array-typed locals anywhere (SROA-safe: zero scratch).
// ---------------------------------------------------------------------------
#define CVT_ACC(T, B) {                                                     \
    f32x2 v;                                                                \
    v.x = __uint_as_float((B) << 16);                                       \
    v.y = __uint_as_float((B) & 0xffff0000u);                               \
    if      ((T) == 0) a0 += v; else if ((T) == 1) a1 += v;                 \
    else if ((T) == 2) a2 += v; else if ((T) == 3) a3 += v;                 \
    else if ((T) == 4) a4 += v; else if ((T) == 5) a5 += v;                 \
    else if ((T) == 6) a6 += v; else               a7 += v; }

#define GATH(BV, S) \
    const uint BV = *(const uint*)(feat + (size_t)(S) * 128 + d2);

#define ACCUM_EDGE(J, BV) \
    { const int et_ = __builtin_amdgcn_readlane(ve, J); CVT_ACC(et_, BV) }

#define STORE_AGG(RR, AV) {                                                 \
    const uint px = (__float_as_uint(AV.x) + 0x8000u) >> 16;                \
    const uint py = (__float_as_uint(AV.y) + 0x8000u) & 0xffff0000u;        \
    *(uint*)&aggHi[n][(RR) * 128 + d2] = px | py; }

#define NODE16_BODY(N_, BASE_LANE)                                          \
    {                                                                       \
        const int n = (N_);                                                 \
        f32x2 a0 = {0.f,0.f}, a1 = {0.f,0.f}, a2 = {0.f,0.f}, a3 = {0.f,0.f};\
        f32x2 a4 = {0.f,0.f}, a5 = {0.f,0.f}, a6 = {0.f,0.f}, a7 = {0.f,0.f};\
        const int s0  = __builtin_amdgcn_readlane(vi, (BASE_LANE) + 0);     \
        const int s1  = __builtin_amdgcn_readlane(vi, (BASE_LANE) + 1);     \
        const int s2  = __builtin_amdgcn_readlane(vi, (BASE_LANE) + 2);     \
        const int s3  = __builtin_amdgcn_readlane(vi, (BASE_LANE) + 3);     \
        const int s4  = __builtin_amdgcn_readlane(vi, (BASE_LANE) + 4);     \
        const int s5  = __builtin_amdgcn_readlane(vi, (BASE_LANE) + 5);     \
        const int s6  = __builtin_amdgcn_readlane(vi, (BASE_LANE) + 6);     \
        const int s7  = __builtin_amdgcn_readlane(vi, (BASE_LANE) + 7);     \
        const int s8  = __builtin_amdgcn_readlane(vi, (BASE_LANE) + 8);     \
        const int s9  = __builtin_amdgcn_readlane(vi, (BASE_LANE) + 9);     \
        const int s10 = __builtin_amdgcn_readlane(vi, (BASE_LANE) + 10);    \
        const int s11 = __builtin_amdgcn_readlane(vi, (BASE_LANE) + 11);    \
        const int s12 = __builtin_amdgcn_readlane(vi, (BASE_LANE) + 12);    \
        const int s13 = __builtin_amdgcn_readlane(vi, (BASE_LANE) + 13);    \
        const int s14 = __builtin_amdgcn_readlane(vi, (BASE_LANE) + 14);    \
        const int s15 = __builtin_amdgcn_readlane(vi, (BASE_LANE) + 15);    \
        GATH(b0,  s0)  GATH(b1,  s1)  GATH(b2,  s2)  GATH(b3,  s3)         \
        GATH(b4,  s4)  GATH(b5,  s5)  GATH(b6,  s6)  GATH(b7,  s7)         \
        GATH(b8,  s8)  GATH(b9,  s9)  GATH(b10, s10) GATH(b11, s11)        \
        GATH(b12, s12) GATH(b13, s13) GATH(b14, s14) GATH(b15, s15)        \
        ACCUM_EDGE((BASE_LANE) + 0,  b0)  ACCUM_EDGE((BASE_LANE) + 1,  b1) \
        ACCUM_EDGE((BASE_LANE) + 2,  b2)  ACCUM_EDGE((BASE_LANE) + 3,  b3) \
        ACCUM_EDGE((BASE_LANE) + 4,  b4)  ACCUM_EDGE((BASE_LANE) + 5,  b5) \
        ACCUM_EDGE((BASE_LANE) + 6,  b6)  ACCUM_EDGE((BASE_LANE) + 7,  b7) \
        ACCUM_EDGE((BASE_LANE) + 8,  b8)  ACCUM_EDGE((BASE_LANE) + 9,  b9) \
        ACCUM_EDGE((BASE_LANE) + 10, b10) ACCUM_EDGE((BASE_LANE) + 11, b11)\
        ACCUM_EDGE((BASE_LANE) + 12, b12) ACCUM_EDGE((BASE_LANE) + 13, b13)\
        ACCUM_EDGE((BASE_LANE) + 14, b14) ACCUM_EDGE((BASE_LANE) + 15, b15)\
        STORE_AGG(0, a0) STORE_AGG(1, a1) STORE_AGG(2, a2) STORE_AGG(3, a3)\
        STORE_AGG(4, a4) STORE_AGG(5, a5) STORE_AGG(6, a6) STORE_AGG(7, a7)\
    }

__device__ __forceinline__ void phaseA_bf16(const ushort* __restrict__ feat,
                                            const int* __restrict__ ptr,
                                            const int* __restrict__ idx,
                                            const int* __restrict__ etype,
                                            int base, ushort (*aggHi)[kLds])
{
    const int lane = threadIdx.x & 63;
    const int wid  = threadIdx.x >> 6;            // 8 waves
    const int d2   = lane * 2;

    const int node0 = base + wid * 2;
    const int p0 = __builtin_amdgcn_readfirstlane(ptr[node0]);
    const int p1 = __builtin_amdgcn_readfirstlane(ptr[node0 + 1]);
    const int p2 = __builtin_amdgcn_readfirstlane(ptr[node0 + 2]);

    if (p1 - p0 == 16 && p2 - p1 == 16) {         // fixed-degree fast path
        const int vi = idx[p0 + (lane & 31)];     // 32 edges cover BOTH nodes
        const int ve = etype[p0 + (lane & 31)];
        NODE16_BODY(wid * 2,     0)
        NODE16_BODY(wid * 2 + 1, 16)
    } else {                                      // generic fallback (never hit)
        #pragma unroll
        for (int t = 0; t < 2; ++t) {
            const int n  = wid * 2 + t;
            const int pa = (t == 0) ? p0 : p1;
            const int pb = (t == 0) ? p1 : p2;
            f32x2 a0 = {0.f,0.f}, a1 = {0.f,0.f}, a2 = {0.f,0.f}, a3 = {0.f,0.f};
            f32x2 a4 = {0.f,0.f}, a5 = {0.f,0.f}, a6 = {0.f,0.f}, a7 = {0.f,0.f};
            for (int e = pa; e < pb; ++e) {
                const int src = __builtin_amdgcn_readfirstlane(idx[e]);
                const int et  = __builtin_amdgcn_readfirstlane(etype[e]);
                const uint u  = *(const uint*)(feat + (size_t)src * 128 + d2);
                CVT_ACC(et, u)
            }
            STORE_AGG(0, a0) STORE_AGG(1, a1) STORE_AGG(2, a2) STORE_AGG(3, a3)
            STORE_AGG(4, a4) STORE_AGG(5, a5) STORE_AGG(6, a6) STORE_AGG(7, a7)
        }
    }
}

// ---------------------------------------------------------------------------
// Layer 1: h1 = bf16( relu(bn( (sum_r agg_r @ W1[r]) / deg )) )
// Phase B: wave w owns n-tile w; dual accumulators break the MFMA dep chain.
// ---------------------------------------------------------------------------
__global__ __launch_bounds__(512, 4)
void rgcn_layer1(const ushort* __restrict__ xb,
                 const ushort* __restrict__ W1hi,
                 const float* __restrict__ gamma, const float* __restrict__ beta,
                 const float* __restrict__ mean,  const float* __restrict__ var,
                 const int* __restrict__ ptr, const int* __restrict__ idx,
                 const int* __restrict__ etype,
                 ushort* __restrict__ h1b)
{
    __shared__ ushort aggHi[kNT][kLds];           // 33 KB
    const int tid  = threadIdx.x;
    const int base = blockIdx.x * kNT;

    phaseA_bf16(xb, ptr, idx, etype, base, aggHi);
    __syncthreads();

    const int lane = tid & 63;
    const int wid  = tid >> 6;                    // n-tile owned by this wave
    const int m    = lane & 15;
    const int q    = lane >> 4;

    const bf16x8* Bh = (const bf16x8*)W1hi + (size_t)wid * 32 * 64 + lane;
    f32x4 accA = {0.f, 0.f, 0.f, 0.f};
    f32x4 accB = {0.f, 0.f, 0.f, 0.f};

    #pragma unroll 4
    for (int kt = 0; kt < 32; kt += 2) {
        const bf16x8 ah0 = *(const bf16x8*)&aggHi[m][kt * 32 + q * 8];
        const bf16x8 bh0 = Bh[(size_t)kt * 64];
        const bf16x8 ah1 = *(const bf16x8*)&aggHi[m][(kt + 1) * 32 + q * 8];
        const bf16x8 bh1 = Bh[(size_t)(kt + 1) * 64];
        accA = __builtin_amdgcn_mfma_f32_16x16x32_bf16(ah0, bh0, accA, 0, 0, 0);
        accB = __builtin_amdgcn_mfma_f32_16x16x32_bf16(ah1, bh1, accB, 0, 0, 0);
    }
    const f32x4 acc = accA + accB;

    // Epilogue: deg norm + BN + ReLU, write bf16 h1
    const int c = wid * 16 + m;
    const float g  = gamma[c] * rsqrtf(var[c] + kBnEps);
    const float mu = mean[c];
    const float bt = beta[c];
    #pragma unroll
    for (int i = 0; i < 4; ++i) {
        const int node = base + q * 4 + i;
        const float invdeg = 1.0f / (float)(ptr[node + 1] - ptr[node]);
        float v = (acc[i] * invdeg - mu) * g + bt;
        v = fmaxf(v, 0.f);
        h1b[(size_t)node * kHid + c] = (ushort)((__float_as_uint(v) + 0x8000u) >> 16);
    }
}

// ---------------------------------------------------------------------------
// Layer 2: out = log_softmax( (sum_r agg_r @ W2[r]) / deg ), N padded 40->48
// ---------------------------------------------------------------------------
__global__ __launch_bounds__(512, 4)
void rgcn_layer2(const ushort* __restrict__ h1b,
                 const ushort* __restrict__ W2hi,
                 const int* __restrict__ ptr, const int* __restrict__ idx,
                 const int* __restrict__ etype,
                 float* __restrict__ out)
{
    __shared__ ushort aggHi[kNT][kLds];           // 33 KB
    __shared__ float logits[kNT][48];             // 3 KB
    const int tid  = threadIdx.x;
    const int base = blockIdx.x * kNT;

    phaseA_bf16(h1b, ptr, idx, etype, base, aggHi);
    __syncthreads();

    const int lane = tid & 63;
    const int wid  = tid >> 6;
    const int m    = lane & 15;
    const int q    = lane >> 4;

    if (wid < 3) {                                // n-tiles 0..2 cover 48 cols
        const bf16x8* Bh = (const bf16x8*)W2hi + (size_t)wid * 32 * 64 + lane;
        f32x4 accA = {0.f, 0.f, 0.f, 0.f};
        f32x4 accB = {0.f, 0.f, 0.f, 0.f};
        #pragma unroll 4
        for (int kt = 0; kt < 32; kt += 2) {
            const bf16x8 ah0 = *(const bf16x8*)&aggHi[m][kt * 32 + q * 8];
            const bf16x8 bh0 = Bh[(size_t)kt * 64];
            const bf16x8 ah1 = *(const bf16x8*)&aggHi[m][(kt + 1) * 32 + q * 8];
            const bf16x8 bh1 = Bh[(size_t)(kt + 1) * 64];
            accA = __builtin_amdgcn_mfma_f32_16x16x32_bf16(ah0, bh0, accA, 0, 0, 0);
            accB = __builtin_amdgcn_mfma_f32_16x16x32_bf16(ah1, bh1, accB, 0, 0, 0);
        }
        const f32x4 acc = accA + accB;
        const int n = wid * 16 + m;               // logit column
        if (n < kOut) {
            #pragma unroll
            for (int i = 0; i < 4; ++i) {
                const int node = base + q * 4 + i;
                const float invdeg = 1.0f / (float)(ptr[node + 1] - ptr[node]);
                logits[q * 4 + i][n] = acc[i] * invdeg;
            }
        }
    }
    __syncthreads();

    // log_softmax: wave w handles nodes w*2, w*2+1
    #pragma unroll
    for (int i = 0; i < 2; ++i) {
        const int nrow = wid * 2 + i;
        const int node = base + nrow;
        const float v = (lane < kOut) ? logits[nrow][lane] : -INFINITY;
        float mx = v;
        #pragma unroll
        for (int off = 32; off > 0; off >>= 1)
            mx = fmaxf(mx, __shfl_xor(mx, off, 64));
        float s = (lane < kOut) ? __expf(v - mx) : 0.f;
        #pragma unroll
        for (int off = 32; off > 0; off >>= 1)
            s += __shfl_xor(s, off, 64);
        if (lane < kOut)
            out[(size_t)node * kOut + lane] = v - mx - __logf(s);
    }
}

// ---------------------------------------------------------------------------
extern "C" void kernel_launch(void* const* d_in, const int* in_sizes, int n_in,
                              void* d_out, int out_size, void* d_ws, size_t ws_size,
                              hipStream_t stream)
{
    const float* x     = (const float*)d_in[0];
    const float* W1    = (const float*)d_in[1];
    const float* W2    = (const float*)d_in[2];
    const float* gamma = (const float*)d_in[3];
    const float* beta  = (const float*)d_in[4];
    const float* mean  = (const float*)d_in[5];
    const float* var   = (const float*)d_in[6];
    const int*   ptr   = (const int*)d_in[7];
    const int*   idx   = (const int*)d_in[8];
    const int*   et    = (const int*)d_in[9];
    float*       out   = (float*)d_out;

    // Workspace (~26 MB)
    char* ws = (char*)d_ws;
    ushort* h1b  = (ushort*)ws;                              // 12,800,000 B
    ushort* xb   = (ushort*)(ws + 12800000);                 // 12,800,000 B
    ushort* W1hi = (ushort*)(ws + 25600000);                 //    262,144 B
    ushort* W2hi = (ushort*)(ws + 25600000 + 262144);        //     98,304 B

    prep<<<dim3(3125 + 64 + 24), dim3(256), 0, stream>>>(x, xb, W1, W1hi, W2, W2hi);

    dim3 grid(kN / kNT), block(512);
    rgcn_layer1<<<grid, block, 0, stream>>>(xb, W1hi, gamma, beta, mean, var,
                                            ptr, idx, et, h1b);
    rgcn_layer2<<<grid, block, 0, stream>>>(h1b, W2hi, ptr, idx, et, out);
}